// Round 3
// baseline (23.817 us; speedup 1.0000x reference)
//
#include <hip/hip_runtime.h>

// Soft-DTW (banded, r1=BIG, R0 finite only at j=0) collapses exactly to the
// diagonal distance sum: out = sum_i sqrt(max(||x_i - y_i||^2, 1e-12)).
// (j advances <=1 per step, R0 finite only at j=0, readout at j=T after T
// steps => unique path j=i; competing softmin branches are ~1e9 away and
// contribute exp(-4e9) == 0 exactly in fp.)
//
// Single kernel node: each block atomicAdds its partial into d_out[0].
// d_out is zeroed via a cheap 4-byte memset node (d_out is poisoned 0xAA
// before timing and never re-poisoned between replays).

#define TN 4096
#define DFN 256
#define ROWS_PER_BLOCK 4
#define NBLK (TN / ROWS_PER_BLOCK)  // 1024 blocks, 4 waves each

__global__ __launch_bounds__(256) void sdtw_diag(const float* __restrict__ x,
                                                 const float* __restrict__ y,
                                                 float* __restrict__ out) {
  const int wave = threadIdx.x >> 6;  // 0..3, one row per wave
  const int lane = threadIdx.x & 63;
  __shared__ float wsum[4];

  const int row = blockIdx.x * ROWS_PER_BLOCK + wave;
  const float4 xv = reinterpret_cast<const float4*>(x)[row * (DFN / 4) + lane];
  const float4 yv = reinterpret_cast<const float4*>(y)[row * (DFN / 4) + lane];
  const float a = xv.x - yv.x;
  const float b = xv.y - yv.y;
  const float c = xv.z - yv.z;
  const float d = xv.w - yv.w;
  float d2 = a * a + b * b + c * c + d * d;
#pragma unroll
  for (int s = 32; s >= 1; s >>= 1) d2 += __shfl_xor(d2, s, 64);

  if (lane == 0) wsum[wave] = sqrtf(fmaxf(d2, 1e-12f));
  __syncthreads();
  if (threadIdx.x == 0)
    atomicAdd(out, (wsum[0] + wsum[1]) + (wsum[2] + wsum[3]));
}

extern "C" void kernel_launch(void* const* d_in, const int* in_sizes, int n_in,
                              void* d_out, int out_size, void* d_ws,
                              size_t ws_size, hipStream_t stream) {
  const float* x = (const float*)d_in[0];
  const float* y = (const float*)d_in[1];
  float* out = (float*)d_out;

  hipMemsetAsync(out, 0, sizeof(float), stream);
  sdtw_diag<<<NBLK, 256, 0, stream>>>(x, y, out);
}